// Round 1
// baseline (375.349 us; speedup 1.0000x reference)
//
#include <hip/hip_runtime.h>

#define N_UNITS 8192
#define N_STEPS 256

// f32 rounding of exp(-0.001/0.01) = exp(-0.1); matches numpy's cast of the
// python float scalar (NEP50 weak-scalar promotion keeps f32 compute).
__device__ const float ALPHA = 0.90483741803595957066f;

// ---------------------------------------------------------------------------
// Kernel A: split-K matvec partials.
//   part[k][c] = sum_{j in chunk k} x[j] * W[j][c]
// Each block: 256 threads x float4 -> 1024 consecutive columns, one row chunk.
// Coalesced 16B/lane loads of W rows; x[j] is wave-uniform (scalar cached).
// ---------------------------------------------------------------------------
__global__ __launch_bounds__(256) void matvec_part_kernel(
    const float* __restrict__ x, const float* __restrict__ W,
    float* __restrict__ part, int rows_per_chunk) {
  const int c0 = blockIdx.x * 1024 + threadIdx.x * 4;
  const int k = blockIdx.y;
  const int j0 = k * rows_per_chunk;

  const float* wp = W + (size_t)j0 * N_UNITS + c0;
  float4 acc = make_float4(0.f, 0.f, 0.f, 0.f);

#pragma unroll 4
  for (int j = 0; j < rows_per_chunk; ++j) {
    const float xj = x[j0 + j];
    const float4 w = *(const float4*)wp;
    acc.x = fmaf(xj, w.x, acc.x);
    acc.y = fmaf(xj, w.y, acc.y);
    acc.z = fmaf(xj, w.z, acc.z);
    acc.w = fmaf(xj, w.w, acc.w);
    wp += N_UNITS;
  }
  *(float4*)(part + (size_t)k * N_UNITS + c0) = acc;
}

// ---------------------------------------------------------------------------
// Kernel B: LIF recurrence, one thread per unit.
//   V' = (ALPHA*V + I) * (1 - Z);  Z' = (V' - thr > 0)
// __fmul_rn/__fadd_rn block FMA contraction so rounding matches numpy exactly
// (spike decisions sit on an exact float compare; one flip = absmax 1.0).
// ---------------------------------------------------------------------------
__global__ __launch_bounds__(64) void lif_kernel(
    const float* __restrict__ part, int chunks, float* __restrict__ out) {
  const int i = blockIdx.x * 64 + threadIdx.x;

  float I = 0.f;
  for (int k = 0; k < chunks; ++k) I += part[(size_t)k * N_UNITS + i];

  float V = 0.f;
  float Z = 0.f;
  for (int t = 0; t < N_STEPS; ++t) {
    const float decayed = __fmul_rn(ALPHA, V);
    const float integ = __fadd_rn(decayed, I);
    V = __fmul_rn(integ, 1.0f - Z);
    // (V - 1 > 0) <=> (V > 1) exactly in f32 (Sterbenz on [0.5,2], monotone
    // outside), so compare without arithmetic.
    Z = (V > 1.0f) ? 1.0f : 0.0f;
    out[t * N_UNITS + i] = Z;
  }
}

extern "C" void kernel_launch(void* const* d_in, const int* in_sizes, int n_in,
                              void* d_out, int out_size, void* d_ws,
                              size_t ws_size, hipStream_t stream) {
  const float* x = (const float*)d_in[0];
  const float* W = (const float*)d_in[1];
  float* out = (float*)d_out;
  float* part = (float*)d_ws;

  // Pick split-K chunk count that fits the workspace (64 -> 2 MB).
  int chunks = 64;
  while (chunks > 1 &&
         (size_t)chunks * N_UNITS * sizeof(float) > ws_size)
    chunks >>= 1;
  const int rows_per_chunk = N_UNITS / chunks;

  dim3 grid_a(N_UNITS / 1024, chunks);
  matvec_part_kernel<<<grid_a, 256, 0, stream>>>(x, W, part, rows_per_chunk);

  lif_kernel<<<N_UNITS / 64, 64, 0, stream>>>(part, chunks, out);
}

// Round 2
// 298.997 us; speedup vs baseline: 1.2554x; 1.2554x over previous
//
#include <hip/hip_runtime.h>

#define N_UNITS 8192
#define N_STEPS 256

// f32 rounding of exp(-0.001/0.01) = exp(-0.1); matches numpy's cast of the
// python float scalar (NEP50 weak-scalar promotion keeps f32 compute).
__device__ const float ALPHA = 0.90483741803595957066f;

// ---------------------------------------------------------------------------
// LIF recurrence, one thread per unit.
//   W == eye(N_UNITS) is a problem constant (reference: "forward_weights
//   forced to eye"), and x @ eye == x bit-exactly in f32 (off-diagonal terms
//   are exact 0.0; 0 + x[i]*1 == x[i] in any summation order). So the input
//   current is just x[i] — no matvec, no workspace.
//
//   V' = (ALPHA*V + I) * (1 - Z);  Z' = (V' - thr > 0)
// __fmul_rn/__fadd_rn block FMA contraction so rounding matches numpy exactly
// (spike decisions sit on an exact float compare; one flip = absmax 1.0).
// (V - 1 > 0) <=> (V > 1) exactly in f32 (Sterbenz on [0.5,2], monotone
// outside), so compare without arithmetic.
// ---------------------------------------------------------------------------
__global__ __launch_bounds__(64) void lif_kernel(
    const float* __restrict__ x, float* __restrict__ out) {
  const int i = blockIdx.x * 64 + threadIdx.x;

  const float I = x[i];

  float V = 0.f;
  float Z = 0.f;
  for (int t = 0; t < N_STEPS; ++t) {
    const float decayed = __fmul_rn(ALPHA, V);
    const float integ = __fadd_rn(decayed, I);
    V = __fmul_rn(integ, 1.0f - Z);
    Z = (V > 1.0f) ? 1.0f : 0.0f;
    out[t * N_UNITS + i] = Z;
  }
}

extern "C" void kernel_launch(void* const* d_in, const int* in_sizes, int n_in,
                              void* d_out, int out_size, void* d_ws,
                              size_t ws_size, hipStream_t stream) {
  const float* x = (const float*)d_in[0];
  float* out = (float*)d_out;

  lif_kernel<<<N_UNITS / 64, 64, 0, stream>>>(x, out);
}